// Round 1
// baseline (141.185 us; speedup 1.0000x reference)
//
#include <hip/hip_runtime.h>

#define NBLK 1024
#define NTHR 256
#define H1_BINS 4096
#define H1_SHIFT 19
#define H2_BINS (1u << H1_SHIFT)      // 524288
#define H2_MASK (H2_BINS - 1u)
#define CHUNK 1024
#define NCHUNK ((int)(H2_BINS / CHUNK))   // 512

// ws layout (bytes):
//   CTRL     [0, 256)        u64[0]=posCount u64[1]=negCount u64[2]=b1 u64[3]=need
//                            u64[4]=k  dbl[5]=posLoss dbl[6]=totLoss
//   H1       [1024, 17408)           4096 x u32
//   H2       [32768, 2129920)        524288 x u32
//   p1part   [2129920, 2146304)      NBLK x 2 doubles (posLoss, totLoss)
//   p2part   [2146304, 2154496)      NBLK doubles (sumAbove)
//   chunkCnt [2154496, 2158592)      512 x u64
//   chunkW   [2158592, 2162688)      512 x double
#define OFF_H1       1024
#define OFF_H2       32768
#define OFF_P1PART   2129920
#define OFF_P2PART   2146304
#define OFF_CCNT     2154496
#define OFF_CW       2158592
#define MEMSET_BYTES 2129920   // ctrl + H1 + H2

__device__ __forceinline__ void elem_compute(float pp, int tt, float mm,
                                             float& loss, bool& pos, bool& neg) {
    bool isz = (tt == 0);
    float logp   = fmaxf(logf(pp),     -100.0f);
    float log1mp = fmaxf(log1pf(-pp),  -100.0f);
    loss = -(isz ? logp : log1mp) * mm;   // (loss_raw) * mask
    float tm = isz ? mm : 0.0f;           // t * mask
    pos = (tm == 1.0f);
    neg = (tm == 0.0f);
}

__global__ __launch_bounds__(NTHR) void pass1(const float* __restrict__ pred,
                                              const int* __restrict__ targ,
                                              const float* __restrict__ mask,
                                              int n, unsigned* __restrict__ gH1,
                                              unsigned long long* __restrict__ ctrl,
                                              double* __restrict__ p1part) {
    __shared__ unsigned shist[H1_BINS];
    __shared__ double sredd[NTHR];
    __shared__ unsigned sredu[NTHR];
    int tid = threadIdx.x;
    for (int i = tid; i < H1_BINS; i += NTHR) shist[i] = 0;
    __syncthreads();

    float posLoss = 0.f, totLoss = 0.f;
    unsigned posCnt = 0, negCnt = 0;

    int nv = n >> 2;
    int gstride = gridDim.x * blockDim.x;
    int g0 = blockIdx.x * blockDim.x + tid;
    const float4* p4 = (const float4*)pred;
    const int4*   t4 = (const int4*)targ;
    const float4* m4 = (const float4*)mask;
    for (int i = g0; i < nv; i += gstride) {
        float4 p = p4[i]; int4 t = t4[i]; float4 m = m4[i];
        float pa[4] = {p.x, p.y, p.z, p.w};
        int   ta[4] = {t.x, t.y, t.z, t.w};
        float ma[4] = {m.x, m.y, m.z, m.w};
        #pragma unroll
        for (int j = 0; j < 4; ++j) {
            float loss; bool pos, neg;
            elem_compute(pa[j], ta[j], ma[j], loss, pos, neg);
            totLoss += loss;
            if (pos) { posCnt++; posLoss += loss; }
            if (neg) {
                negCnt++;
                unsigned u = __float_as_uint(loss);
                if (u & 0x80000000u) u = 0u;   // -0 (or pathological negatives) -> 0
                atomicAdd(&shist[u >> H1_SHIFT], 1u);
            }
        }
    }
    // scalar tail (N % 4)
    for (int i = (nv << 2) + g0; i < n; i += gstride) {
        float loss; bool pos, neg;
        elem_compute(pred[i], targ[i], mask[i], loss, pos, neg);
        totLoss += loss;
        if (pos) { posCnt++; posLoss += loss; }
        if (neg) {
            negCnt++;
            unsigned u = __float_as_uint(loss);
            if (u & 0x80000000u) u = 0u;
            atomicAdd(&shist[u >> H1_SHIFT], 1u);
        }
    }
    __syncthreads();
    // merge LDS histogram -> global (skip empty bins)
    for (int i = tid; i < H1_BINS; i += NTHR) {
        unsigned c = shist[i];
        if (c) atomicAdd(&gH1[i], c);
    }
    // deterministic block reductions
    sredd[tid] = (double)posLoss; __syncthreads();
    for (int s = NTHR / 2; s > 0; s >>= 1) { if (tid < s) sredd[tid] += sredd[tid + s]; __syncthreads(); }
    if (tid == 0) p1part[2 * blockIdx.x] = sredd[0];
    __syncthreads();
    sredd[tid] = (double)totLoss; __syncthreads();
    for (int s = NTHR / 2; s > 0; s >>= 1) { if (tid < s) sredd[tid] += sredd[tid + s]; __syncthreads(); }
    if (tid == 0) p1part[2 * blockIdx.x + 1] = sredd[0];
    __syncthreads();
    sredu[tid] = posCnt; __syncthreads();
    for (int s = NTHR / 2; s > 0; s >>= 1) { if (tid < s) sredu[tid] += sredu[tid + s]; __syncthreads(); }
    if (tid == 0) atomicAdd(&ctrl[0], (unsigned long long)sredu[0]);
    __syncthreads();
    sredu[tid] = negCnt; __syncthreads();
    for (int s = NTHR / 2; s > 0; s >>= 1) { if (tid < s) sredu[tid] += sredu[tid + s]; __syncthreads(); }
    if (tid == 0) atomicAdd(&ctrl[1], (unsigned long long)sredu[0]);
}

__global__ __launch_bounds__(1024) void findbin(const unsigned* __restrict__ gH1,
                                                unsigned long long* __restrict__ ctrl,
                                                const double* __restrict__ p1part) {
    __shared__ double sd[1024];
    __shared__ unsigned long long ss[1024];
    int tid = threadIdx.x;
    // reduce posLoss partials (NBLK == 1024)
    sd[tid] = p1part[2 * tid]; __syncthreads();
    for (int s = 512; s > 0; s >>= 1) { if (tid < s) sd[tid] += sd[tid + s]; __syncthreads(); }
    double posLoss = sd[0]; __syncthreads();
    sd[tid] = p1part[2 * tid + 1]; __syncthreads();
    for (int s = 512; s > 0; s >>= 1) { if (tid < s) sd[tid] += sd[tid + s]; __syncthreads(); }
    double totLoss = sd[0]; __syncthreads();

    unsigned long long posCnt = ctrl[0];
    unsigned long long negCnt = ctrl[1];
    unsigned long long k = posCnt * 5ULL;
    if (k > negCnt) k = negCnt;

    // suffix scan of 4096-bin histogram (4 bins / thread)
    int base = tid * 4;
    unsigned h0 = gH1[base], h1 = gH1[base + 1], h2 = gH1[base + 2], h3 = gH1[base + 3];
    unsigned long long mysum = (unsigned long long)h0 + h1 + h2 + h3;
    ss[tid] = mysum; __syncthreads();
    for (int d = 1; d < 1024; d <<= 1) {
        unsigned long long add = (tid + d < 1024) ? ss[tid + d] : 0ULL;
        __syncthreads();
        ss[tid] += add;
        __syncthreads();
    }
    unsigned long long run = (tid == 1023) ? 0ULL : ss[tid + 1];
    if (k > 0) {
        unsigned hh[4] = {h3, h2, h1, h0};
        int off[4] = {3, 2, 1, 0};
        #pragma unroll
        for (int j = 0; j < 4; ++j) {
            unsigned long long c = hh[j];
            if (run < k && k <= run + c) {
                ctrl[2] = (unsigned long long)(base + off[j]);  // b1
                ctrl[3] = k - run;                              // need (within-bin)
            }
            run += c;
        }
    } else if (tid == 0) {
        ctrl[2] = (unsigned long long)H1_BINS;  // sentinel: no selection
        ctrl[3] = 0;
    }
    if (tid == 0) {
        ctrl[4] = k;
        ((double*)ctrl)[5] = posLoss;
        ((double*)ctrl)[6] = totLoss;
    }
}

__global__ __launch_bounds__(NTHR) void pass2(const float* __restrict__ pred,
                                              const int* __restrict__ targ,
                                              const float* __restrict__ mask,
                                              int n,
                                              const unsigned long long* __restrict__ ctrl,
                                              unsigned* __restrict__ gH2,
                                              double* __restrict__ p2part) {
    __shared__ double sredd[NTHR];
    int tid = threadIdx.x;
    unsigned b1 = (unsigned)ctrl[2];
    float acc = 0.f;
    int nv = n >> 2;
    int gstride = gridDim.x * blockDim.x;
    int g0 = blockIdx.x * blockDim.x + tid;
    const float4* p4 = (const float4*)pred;
    const int4*   t4 = (const int4*)targ;
    const float4* m4 = (const float4*)mask;
    for (int i = g0; i < nv; i += gstride) {
        float4 p = p4[i]; int4 t = t4[i]; float4 m = m4[i];
        float pa[4] = {p.x, p.y, p.z, p.w};
        int   ta[4] = {t.x, t.y, t.z, t.w};
        float ma[4] = {m.x, m.y, m.z, m.w};
        #pragma unroll
        for (int j = 0; j < 4; ++j) {
            float loss; bool pos, neg;
            elem_compute(pa[j], ta[j], ma[j], loss, pos, neg);
            if (neg) {
                unsigned u = __float_as_uint(loss);
                if (u & 0x80000000u) u = 0u;
                unsigned bin = u >> H1_SHIFT;
                if (bin > b1) acc += loss;
                else if (bin == b1) atomicAdd(&gH2[u & H2_MASK], 1u);
            }
        }
    }
    for (int i = (nv << 2) + g0; i < n; i += gstride) {
        float loss; bool pos, neg;
        elem_compute(pred[i], targ[i], mask[i], loss, pos, neg);
        if (neg) {
            unsigned u = __float_as_uint(loss);
            if (u & 0x80000000u) u = 0u;
            unsigned bin = u >> H1_SHIFT;
            if (bin > b1) acc += loss;
            else if (bin == b1) atomicAdd(&gH2[u & H2_MASK], 1u);
        }
    }
    sredd[tid] = (double)acc; __syncthreads();
    for (int s = NTHR / 2; s > 0; s >>= 1) { if (tid < s) sredd[tid] += sredd[tid + s]; __syncthreads(); }
    if (tid == 0) p2part[blockIdx.x] = sredd[0];
}

__global__ __launch_bounds__(256) void chunkscan(const unsigned* __restrict__ gH2,
                                                 const unsigned long long* __restrict__ ctrl,
                                                 unsigned long long* __restrict__ chunkCnt,
                                                 double* __restrict__ chunkW) {
    __shared__ unsigned long long sc[256];
    __shared__ double sw[256];
    int tid = threadIdx.x;
    unsigned b1 = (unsigned)ctrl[2];
    int base = blockIdx.x * CHUNK;
    unsigned long long cnt = 0; double w = 0.0;
    if (b1 < H1_BINS) {
        for (int i = tid; i < CHUNK; i += 256) {
            unsigned c = gH2[base + i];
            if (c) {
                float L = __uint_as_float((b1 << H1_SHIFT) | (unsigned)(base + i));
                cnt += c;
                w += (double)c * (double)L;
            }
        }
    }
    sc[tid] = cnt; sw[tid] = w; __syncthreads();
    for (int s = 128; s > 0; s >>= 1) {
        if (tid < s) { sc[tid] += sc[tid + s]; sw[tid] += sw[tid + s]; }
        __syncthreads();
    }
    if (tid == 0) { chunkCnt[blockIdx.x] = sc[0]; chunkW[blockIdx.x] = sw[0]; }
}

__global__ __launch_bounds__(512) void finalize(const unsigned* __restrict__ gH2,
                                                const unsigned long long* __restrict__ ctrl,
                                                const double* __restrict__ p2part,
                                                const unsigned long long* __restrict__ chunkCnt,
                                                const double* __restrict__ chunkW,
                                                float* __restrict__ out, int n) {
    __shared__ double sd[512];
    __shared__ unsigned long long sc[512];
    __shared__ double sw[512];
    __shared__ int s_cstar;
    __shared__ unsigned long long s_rem;
    __shared__ double s_wAbove;
    __shared__ double s_res;
    int tid = threadIdx.x;

    // reduce P2 partials (NBLK = 1024, 512 threads -> 2 each)
    sd[tid] = p2part[tid] + p2part[tid + 512]; __syncthreads();
    for (int s = 256; s > 0; s >>= 1) { if (tid < s) sd[tid] += sd[tid + s]; __syncthreads(); }
    double sumAbove = sd[0]; __syncthreads();

    unsigned long long posCnt = ctrl[0];
    unsigned long long b1 = ctrl[2];
    unsigned long long need = ctrl[3];
    unsigned long long k = ctrl[4];
    double posLoss = ((const double*)ctrl)[5];
    double totLoss = ((const double*)ctrl)[6];

    double negLoss = sumAbove;

    if (need > 0) {
        if (tid == 0) { s_cstar = 0; s_rem = 1; s_wAbove = 0.0; s_res = 0.0; }
        unsigned long long myc = chunkCnt[tid];
        double myw = chunkW[tid];
        sc[tid] = myc; sw[tid] = myw; __syncthreads();
        for (int d = 1; d < 512; d <<= 1) {
            unsigned long long ac = (tid + d < 512) ? sc[tid + d] : 0ULL;
            double aw = (tid + d < 512) ? sw[tid + d] : 0.0;
            __syncthreads();
            sc[tid] += ac; sw[tid] += aw;
            __syncthreads();
        }
        unsigned long long afterC = (tid == 511) ? 0ULL : sc[tid + 1];
        double afterW = (tid == 511) ? 0.0 : sw[tid + 1];
        if (afterC < need && need <= afterC + myc) {
            s_cstar = tid; s_rem = need - afterC; s_wAbove = afterW;
        }
        __syncthreads();
        int cstar = s_cstar;
        unsigned long long rem = s_rem;
        double wAbove = s_wAbove;
        __syncthreads();  // done reading scan-1 results before reuse

        int pb = cstar * CHUNK + 2 * tid;
        unsigned c0 = gH2[pb], c1 = gH2[pb + 1];
        float L0 = __uint_as_float(((unsigned)b1 << H1_SHIFT) | (unsigned)pb);
        float L1 = __uint_as_float(((unsigned)b1 << H1_SHIFT) | (unsigned)(pb + 1));
        sc[tid] = (unsigned long long)c0 + c1;
        sw[tid] = (double)c0 * (double)L0 + (double)c1 * (double)L1;
        __syncthreads();
        for (int d = 1; d < 512; d <<= 1) {
            unsigned long long ac = (tid + d < 512) ? sc[tid + d] : 0ULL;
            double aw = (tid + d < 512) ? sw[tid + d] : 0.0;
            __syncthreads();
            sc[tid] += ac; sw[tid] += aw;
            __syncthreads();
        }
        unsigned long long run = (tid == 511) ? 0ULL : sc[tid + 1];
        double wrun = (tid == 511) ? 0.0 : sw[tid + 1];
        // walk own 2 patterns, higher first
        if (run < rem && rem <= run + c1) {
            s_res = wrun + (double)(rem - run) * (double)L1;
        }
        run += c1; wrun += (double)c1 * (double)L1;
        if (run < rem && rem <= run + c0) {
            s_res = wrun + (double)(rem - run) * (double)L0;
        }
        __syncthreads();
        negLoss += wAbove + s_res;
    }

    if (tid == 0) {
        double result;
        if (posCnt == 0) {
            result = totLoss / (double)n;
        } else {
            result = (posLoss + negLoss) / ((double)posCnt + (double)k + 1e-8);
        }
        out[0] = (float)result;
    }
}

extern "C" void kernel_launch(void* const* d_in, const int* in_sizes, int n_in,
                              void* d_out, int out_size, void* d_ws, size_t ws_size,
                              hipStream_t stream) {
    const float* pred = (const float*)d_in[0];
    const int*   targ = (const int*)d_in[1];
    const float* mask = (const float*)d_in[2];
    int n = in_sizes[0];

    char* ws = (char*)d_ws;
    unsigned long long* ctrl = (unsigned long long*)ws;
    unsigned* gH1 = (unsigned*)(ws + OFF_H1);
    unsigned* gH2 = (unsigned*)(ws + OFF_H2);
    double* p1part = (double*)(ws + OFF_P1PART);
    double* p2part = (double*)(ws + OFF_P2PART);
    unsigned long long* chunkCnt = (unsigned long long*)(ws + OFF_CCNT);
    double* chunkW = (double*)(ws + OFF_CW);

    hipMemsetAsync(d_ws, 0, MEMSET_BYTES, stream);

    pass1<<<NBLK, NTHR, 0, stream>>>(pred, targ, mask, n, gH1, ctrl, p1part);
    findbin<<<1, 1024, 0, stream>>>(gH1, ctrl, p1part);
    pass2<<<NBLK, NTHR, 0, stream>>>(pred, targ, mask, n, ctrl, gH2, p2part);
    chunkscan<<<NCHUNK, 256, 0, stream>>>(gH2, ctrl, chunkCnt, chunkW);
    finalize<<<1, 512, 0, stream>>>(gH2, ctrl, p2part, chunkCnt, chunkW, (float*)d_out, n);
}

// Round 4
// 99.712 us; speedup vs baseline: 1.4159x; 1.4159x over previous
//
#include <hip/hip_runtime.h>

#define NBLK 1024
#define NTHR 256
#define H1_BINS 4096
#define H1_SHIFT 19
#define H2_BINS (1u << H1_SHIFT)      // 524288
#define H2_MASK (H2_BINS - 1u)
#define CHUNK 1024
#define NCHUNK ((int)(H2_BINS / CHUNK))   // 512

// ws layout (bytes):
//   CTRL     [0, 256)        u64[0]=posCount u64[1]=negCount u64[2]=b1 u64[3]=need
//                            u64[4]=k  dbl[5]=posLoss dbl[6]=totLoss
//   H1       [1024, 17408)           4096 x u32
//   H2       [32768, 2129920)        524288 x u32
//   p1part   [2129920, 2146304)      NBLK x 2 doubles (posLoss, totLoss)
//   p2part   [2146304, 2154496)      NBLK doubles (sumAbove)
//   chunkCnt [2154496, 2158592)      512 x u64
//   chunkW   [2158592, 2162688)      512 x double
//   lossBits [4194304, 4194304+4n)   n x u32  (only if ws_size permits)
#define OFF_H1       1024
#define OFF_H2       32768
#define OFF_P1PART   2129920
#define OFF_P2PART   2146304
#define OFF_CCNT     2154496
#define OFF_CW       2158592
#define OFF_LOSS     4194304
#define MEMSET_BYTES 2129920   // ctrl + H1 + H2

#define LN2F 0.69314718055994531f

// loss = min(-log(x), 100) * m  with x = (t==0 ? p : 1-p); single v_log_f32.
__device__ __forceinline__ void elem_compute(float pp, int tt, float mm,
                                             float& loss, bool& pos, bool& neg) {
    bool isz = (tt == 0);
    float x = isz ? pp : (1.0f - pp);
    float lr = fminf(-__log2f(x) * LN2F, 100.0f);   // >= 0 always; log2(0) = -inf -> 100
    loss = lr * mm;
    float tm = isz ? mm : 0.0f;           // t * mask
    pos = (tm == 1.0f);
    neg = (tm == 0.0f);
}

template <bool STORE>
__global__ __launch_bounds__(NTHR) void pass1(const float* __restrict__ pred,
                                              const int* __restrict__ targ,
                                              const float* __restrict__ mask,
                                              int n, unsigned* __restrict__ gH1,
                                              unsigned long long* __restrict__ ctrl,
                                              double* __restrict__ p1part,
                                              unsigned* __restrict__ lossOut) {
    __shared__ unsigned shist[H1_BINS];
    __shared__ double sredd[NTHR];
    __shared__ unsigned sredu[NTHR];
    int tid = threadIdx.x;
    for (int i = tid; i < H1_BINS; i += NTHR) shist[i] = 0;
    __syncthreads();

    float posLoss = 0.f, totLoss = 0.f;
    unsigned posCnt = 0, negCnt = 0;

    int nv = n >> 2;
    int gstride = gridDim.x * blockDim.x;
    int g0 = blockIdx.x * blockDim.x + tid;
    const float4* p4 = (const float4*)pred;
    const int4*   t4 = (const int4*)targ;
    const float4* m4 = (const float4*)mask;
    uint4* l4 = (uint4*)lossOut;
    for (int i = g0; i < nv; i += gstride) {
        float4 p = p4[i]; int4 t = t4[i]; float4 m = m4[i];
        float pa[4] = {p.x, p.y, p.z, p.w};
        int   ta[4] = {t.x, t.y, t.z, t.w};
        float ma[4] = {m.x, m.y, m.z, m.w};
        unsigned ua[4];
        #pragma unroll
        for (int j = 0; j < 4; ++j) {
            float loss; bool pos, neg;
            elem_compute(pa[j], ta[j], ma[j], loss, pos, neg);
            totLoss += loss;
            if (pos) { posCnt++; posLoss += loss; }
            unsigned u = __float_as_uint(loss);
            if (u & 0x80000000u) u = 0u;   // -0 -> 0
            if (neg) {
                negCnt++;
                atomicAdd(&shist[u >> H1_SHIFT], 1u);
            } else {
                u = 0x80000000u;           // sentinel: not a negative
            }
            ua[j] = u;
        }
        if (STORE) {
            uint4 st; st.x = ua[0]; st.y = ua[1]; st.z = ua[2]; st.w = ua[3];
            l4[i] = st;
        }
    }
    // scalar tail (N % 4)
    for (int i = (nv << 2) + g0; i < n; i += gstride) {
        float loss; bool pos, neg;
        elem_compute(pred[i], targ[i], mask[i], loss, pos, neg);
        totLoss += loss;
        if (pos) { posCnt++; posLoss += loss; }
        unsigned u = __float_as_uint(loss);
        if (u & 0x80000000u) u = 0u;
        if (neg) {
            negCnt++;
            atomicAdd(&shist[u >> H1_SHIFT], 1u);
        } else {
            u = 0x80000000u;
        }
        if (STORE) lossOut[i] = u;
    }
    __syncthreads();
    // merge LDS histogram -> global (skip empty bins)
    for (int i = tid; i < H1_BINS; i += NTHR) {
        unsigned c = shist[i];
        if (c) atomicAdd(&gH1[i], c);
    }
    // deterministic block reductions
    sredd[tid] = (double)posLoss; __syncthreads();
    for (int s = NTHR / 2; s > 0; s >>= 1) { if (tid < s) sredd[tid] += sredd[tid + s]; __syncthreads(); }
    if (tid == 0) p1part[2 * blockIdx.x] = sredd[0];
    __syncthreads();
    sredd[tid] = (double)totLoss; __syncthreads();
    for (int s = NTHR / 2; s > 0; s >>= 1) { if (tid < s) sredd[tid] += sredd[tid + s]; __syncthreads(); }
    if (tid == 0) p1part[2 * blockIdx.x + 1] = sredd[0];
    __syncthreads();
    sredu[tid] = posCnt; __syncthreads();
    for (int s = NTHR / 2; s > 0; s >>= 1) { if (tid < s) sredu[tid] += sredu[tid + s]; __syncthreads(); }
    if (tid == 0) atomicAdd(&ctrl[0], (unsigned long long)sredu[0]);
    __syncthreads();
    sredu[tid] = negCnt; __syncthreads();
    for (int s = NTHR / 2; s > 0; s >>= 1) { if (tid < s) sredu[tid] += sredu[tid + s]; __syncthreads(); }
    if (tid == 0) atomicAdd(&ctrl[1], (unsigned long long)sredu[0]);
}

__global__ __launch_bounds__(1024) void findbin(const unsigned* __restrict__ gH1,
                                                unsigned long long* __restrict__ ctrl,
                                                const double* __restrict__ p1part) {
    __shared__ double sd[1024];
    __shared__ unsigned long long ss[1024];
    int tid = threadIdx.x;
    sd[tid] = p1part[2 * tid]; __syncthreads();
    for (int s = 512; s > 0; s >>= 1) { if (tid < s) sd[tid] += sd[tid + s]; __syncthreads(); }
    double posLoss = sd[0]; __syncthreads();
    sd[tid] = p1part[2 * tid + 1]; __syncthreads();
    for (int s = 512; s > 0; s >>= 1) { if (tid < s) sd[tid] += sd[tid + s]; __syncthreads(); }
    double totLoss = sd[0]; __syncthreads();

    unsigned long long posCnt = ctrl[0];
    unsigned long long negCnt = ctrl[1];
    unsigned long long k = posCnt * 5ULL;
    if (k > negCnt) k = negCnt;

    int base = tid * 4;
    unsigned h0 = gH1[base], h1 = gH1[base + 1], h2 = gH1[base + 2], h3 = gH1[base + 3];
    unsigned long long mysum = (unsigned long long)h0 + h1 + h2 + h3;
    ss[tid] = mysum; __syncthreads();
    for (int d = 1; d < 1024; d <<= 1) {
        unsigned long long add = (tid + d < 1024) ? ss[tid + d] : 0ULL;
        __syncthreads();
        ss[tid] += add;
        __syncthreads();
    }
    unsigned long long run = (tid == 1023) ? 0ULL : ss[tid + 1];
    if (k > 0) {
        unsigned hh[4] = {h3, h2, h1, h0};
        int off[4] = {3, 2, 1, 0};
        #pragma unroll
        for (int j = 0; j < 4; ++j) {
            unsigned long long c = hh[j];
            if (run < k && k <= run + c) {
                ctrl[2] = (unsigned long long)(base + off[j]);  // b1
                ctrl[3] = k - run;                              // need (within-bin)
            }
            run += c;
        }
    } else if (tid == 0) {
        ctrl[2] = (unsigned long long)H1_BINS;  // sentinel: no selection
        ctrl[3] = 0;
    }
    if (tid == 0) {
        ctrl[4] = k;
        ((double*)ctrl)[5] = posLoss;
        ((double*)ctrl)[6] = totLoss;
    }
}

// pass2 from stored loss bits (64 MB read, no recompute)
__global__ __launch_bounds__(NTHR) void pass2s(const unsigned* __restrict__ lossBits,
                                               int n,
                                               const unsigned long long* __restrict__ ctrl,
                                               unsigned* __restrict__ gH2,
                                               double* __restrict__ p2part) {
    __shared__ double sredd[NTHR];
    int tid = threadIdx.x;
    unsigned b1 = (unsigned)ctrl[2];
    float acc = 0.f;
    int nv = n >> 2;
    int gstride = gridDim.x * blockDim.x;
    int g0 = blockIdx.x * blockDim.x + tid;
    const uint4* l4 = (const uint4*)lossBits;
    for (int i = g0; i < nv; i += gstride) {
        uint4 v = l4[i];
        unsigned ua[4] = {v.x, v.y, v.z, v.w};
        #pragma unroll
        for (int j = 0; j < 4; ++j) {
            unsigned u = ua[j];
            if (!(u & 0x80000000u)) {
                unsigned bin = u >> H1_SHIFT;
                if (bin > b1) acc += __uint_as_float(u);
                else if (bin == b1) atomicAdd(&gH2[u & H2_MASK], 1u);
            }
        }
    }
    for (int i = (nv << 2) + g0; i < n; i += gstride) {
        unsigned u = lossBits[i];
        if (!(u & 0x80000000u)) {
            unsigned bin = u >> H1_SHIFT;
            if (bin > b1) acc += __uint_as_float(u);
            else if (bin == b1) atomicAdd(&gH2[u & H2_MASK], 1u);
        }
    }
    sredd[tid] = (double)acc; __syncthreads();
    for (int s = NTHR / 2; s > 0; s >>= 1) { if (tid < s) sredd[tid] += sredd[tid + s]; __syncthreads(); }
    if (tid == 0) p2part[blockIdx.x] = sredd[0];
}

// fallback pass2: recompute losses from inputs
__global__ __launch_bounds__(NTHR) void pass2(const float* __restrict__ pred,
                                              const int* __restrict__ targ,
                                              const float* __restrict__ mask,
                                              int n,
                                              const unsigned long long* __restrict__ ctrl,
                                              unsigned* __restrict__ gH2,
                                              double* __restrict__ p2part) {
    __shared__ double sredd[NTHR];
    int tid = threadIdx.x;
    unsigned b1 = (unsigned)ctrl[2];
    float acc = 0.f;
    int nv = n >> 2;
    int gstride = gridDim.x * blockDim.x;
    int g0 = blockIdx.x * blockDim.x + tid;
    const float4* p4 = (const float4*)pred;
    const int4*   t4 = (const int4*)targ;
    const float4* m4 = (const float4*)mask;
    for (int i = g0; i < nv; i += gstride) {
        float4 p = p4[i]; int4 t = t4[i]; float4 m = m4[i];
        float pa[4] = {p.x, p.y, p.z, p.w};
        int   ta[4] = {t.x, t.y, t.z, t.w};
        float ma[4] = {m.x, m.y, m.z, m.w};
        #pragma unroll
        for (int j = 0; j < 4; ++j) {
            float loss; bool pos, neg;
            elem_compute(pa[j], ta[j], ma[j], loss, pos, neg);
            if (neg) {
                unsigned u = __float_as_uint(loss);
                if (u & 0x80000000u) u = 0u;
                unsigned bin = u >> H1_SHIFT;
                if (bin > b1) acc += loss;
                else if (bin == b1) atomicAdd(&gH2[u & H2_MASK], 1u);
            }
        }
    }
    for (int i = (nv << 2) + g0; i < n; i += gstride) {
        float loss; bool pos, neg;
        elem_compute(pred[i], targ[i], mask[i], loss, pos, neg);
        if (neg) {
            unsigned u = __float_as_uint(loss);
            if (u & 0x80000000u) u = 0u;
            unsigned bin = u >> H1_SHIFT;
            if (bin > b1) acc += loss;
            else if (bin == b1) atomicAdd(&gH2[u & H2_MASK], 1u);
        }
    }
    sredd[tid] = (double)acc; __syncthreads();
    for (int s = NTHR / 2; s > 0; s >>= 1) { if (tid < s) sredd[tid] += sredd[tid + s]; __syncthreads(); }
    if (tid == 0) p2part[blockIdx.x] = sredd[0];
}

__global__ __launch_bounds__(256) void chunkscan(const unsigned* __restrict__ gH2,
                                                 const unsigned long long* __restrict__ ctrl,
                                                 unsigned long long* __restrict__ chunkCnt,
                                                 double* __restrict__ chunkW) {
    __shared__ unsigned long long sc[256];
    __shared__ double sw[256];
    int tid = threadIdx.x;
    unsigned b1 = (unsigned)ctrl[2];
    int base = blockIdx.x * CHUNK;
    unsigned long long cnt = 0; double w = 0.0;
    if (b1 < H1_BINS) {
        for (int i = tid; i < CHUNK; i += 256) {
            unsigned c = gH2[base + i];
            if (c) {
                float L = __uint_as_float((b1 << H1_SHIFT) | (unsigned)(base + i));
                cnt += c;
                w += (double)c * (double)L;
            }
        }
    }
    sc[tid] = cnt; sw[tid] = w; __syncthreads();
    for (int s = 128; s > 0; s >>= 1) {
        if (tid < s) { sc[tid] += sc[tid + s]; sw[tid] += sw[tid + s]; }
        __syncthreads();
    }
    if (tid == 0) { chunkCnt[blockIdx.x] = sc[0]; chunkW[blockIdx.x] = sw[0]; }
}

__global__ __launch_bounds__(512) void finalize(const unsigned* __restrict__ gH2,
                                                const unsigned long long* __restrict__ ctrl,
                                                const double* __restrict__ p2part,
                                                const unsigned long long* __restrict__ chunkCnt,
                                                const double* __restrict__ chunkW,
                                                float* __restrict__ out, int n) {
    __shared__ double sd[512];
    __shared__ unsigned long long sc[512];
    __shared__ double sw[512];
    __shared__ int s_cstar;
    __shared__ unsigned long long s_rem;
    __shared__ double s_wAbove;
    __shared__ double s_res;
    int tid = threadIdx.x;

    sd[tid] = p2part[tid] + p2part[tid + 512]; __syncthreads();
    for (int s = 256; s > 0; s >>= 1) { if (tid < s) sd[tid] += sd[tid + s]; __syncthreads(); }
    double sumAbove = sd[0]; __syncthreads();

    unsigned long long posCnt = ctrl[0];
    unsigned long long b1 = ctrl[2];
    unsigned long long need = ctrl[3];
    unsigned long long k = ctrl[4];
    double posLoss = ((const double*)ctrl)[5];
    double totLoss = ((const double*)ctrl)[6];

    double negLoss = sumAbove;

    if (need > 0) {
        if (tid == 0) { s_cstar = 0; s_rem = 1; s_wAbove = 0.0; s_res = 0.0; }
        unsigned long long myc = chunkCnt[tid];
        double myw = chunkW[tid];
        sc[tid] = myc; sw[tid] = myw; __syncthreads();
        for (int d = 1; d < 512; d <<= 1) {
            unsigned long long ac = (tid + d < 512) ? sc[tid + d] : 0ULL;
            double aw = (tid + d < 512) ? sw[tid + d] : 0.0;
            __syncthreads();
            sc[tid] += ac; sw[tid] += aw;
            __syncthreads();
        }
        unsigned long long afterC = (tid == 511) ? 0ULL : sc[tid + 1];
        double afterW = (tid == 511) ? 0.0 : sw[tid + 1];
        if (afterC < need && need <= afterC + myc) {
            s_cstar = tid; s_rem = need - afterC; s_wAbove = afterW;
        }
        __syncthreads();
        int cstar = s_cstar;
        unsigned long long rem = s_rem;
        double wAbove = s_wAbove;
        __syncthreads();

        int pb = cstar * CHUNK + 2 * tid;
        unsigned c0 = gH2[pb], c1 = gH2[pb + 1];
        float L0 = __uint_as_float(((unsigned)b1 << H1_SHIFT) | (unsigned)pb);
        float L1 = __uint_as_float(((unsigned)b1 << H1_SHIFT) | (unsigned)(pb + 1));
        sc[tid] = (unsigned long long)c0 + c1;
        sw[tid] = (double)c0 * (double)L0 + (double)c1 * (double)L1;
        __syncthreads();
        for (int d = 1; d < 512; d <<= 1) {
            unsigned long long ac = (tid + d < 512) ? sc[tid + d] : 0ULL;
            double aw = (tid + d < 512) ? sw[tid + d] : 0.0;
            __syncthreads();
            sc[tid] += ac; sw[tid] += aw;
            __syncthreads();
        }
        unsigned long long run = (tid == 511) ? 0ULL : sc[tid + 1];
        double wrun = (tid == 511) ? 0.0 : sw[tid + 1];
        if (run < rem && rem <= run + c1) {
            s_res = wrun + (double)(rem - run) * (double)L1;
        }
        run += c1; wrun += (double)c1 * (double)L1;
        if (run < rem && rem <= run + c0) {
            s_res = wrun + (double)(rem - run) * (double)L0;
        }
        __syncthreads();
        negLoss += wAbove + s_res;
    }

    if (tid == 0) {
        double result;
        if (posCnt == 0) {
            result = totLoss / (double)n;
        } else {
            result = (posLoss + negLoss) / ((double)posCnt + (double)k + 1e-8);
        }
        out[0] = (float)result;
    }
}

extern "C" void kernel_launch(void* const* d_in, const int* in_sizes, int n_in,
                              void* d_out, int out_size, void* d_ws, size_t ws_size,
                              hipStream_t stream) {
    const float* pred = (const float*)d_in[0];
    const int*   targ = (const int*)d_in[1];
    const float* mask = (const float*)d_in[2];
    int n = in_sizes[0];

    char* ws = (char*)d_ws;
    unsigned long long* ctrl = (unsigned long long*)ws;
    unsigned* gH1 = (unsigned*)(ws + OFF_H1);
    unsigned* gH2 = (unsigned*)(ws + OFF_H2);
    double* p1part = (double*)(ws + OFF_P1PART);
    double* p2part = (double*)(ws + OFF_P2PART);
    unsigned long long* chunkCnt = (unsigned long long*)(ws + OFF_CCNT);
    double* chunkW = (double*)(ws + OFF_CW);
    unsigned* lossBits = (unsigned*)(ws + OFF_LOSS);

    bool store = ws_size >= (size_t)OFF_LOSS + (size_t)n * 4ull;

    hipMemsetAsync(d_ws, 0, MEMSET_BYTES, stream);

    if (store) {
        pass1<true><<<NBLK, NTHR, 0, stream>>>(pred, targ, mask, n, gH1, ctrl, p1part, lossBits);
        findbin<<<1, 1024, 0, stream>>>(gH1, ctrl, p1part);
        pass2s<<<NBLK, NTHR, 0, stream>>>(lossBits, n, ctrl, gH2, p2part);
    } else {
        pass1<false><<<NBLK, NTHR, 0, stream>>>(pred, targ, mask, n, gH1, ctrl, p1part, lossBits);
        findbin<<<1, 1024, 0, stream>>>(gH1, ctrl, p1part);
        pass2<<<NBLK, NTHR, 0, stream>>>(pred, targ, mask, n, ctrl, gH2, p2part);
    }
    chunkscan<<<NCHUNK, 256, 0, stream>>>(gH2, ctrl, chunkCnt, chunkW);
    finalize<<<1, 512, 0, stream>>>(gH2, ctrl, p2part, chunkCnt, chunkW, (float*)d_out, n);
}